// Round 7
// baseline (100.229 us; speedup 1.0000x reference)
//
#include <hip/hip_runtime.h>
#include <math.h>

#define B 1024
#define O 256
#define D 1024
#define ALPHA 0.005f

#define OT 4             // o-groups per thread (o = lane + 64*g)
#define KB 4             // b rows per wave
#define WV 4             // waves per block
#define BB (KB * WV)     // 16 b rows per block
#define DS 16            // D splits (blockIdx.y)
#define DCH (D / DS)     // 64 d per block
#define NQ  (DCH / 4)    // 16 float4 steps

// Kernel 0: transpose c[O][D] -> ct[D/4][O] (float4 elements)
__global__ __launch_bounds__(256) void transpose_c(const float* __restrict__ c,
                                                   float4* __restrict__ ct)
{
    const int o  = threadIdx.x;         // 0..255
    const int d4 = blockIdx.x;          // 0..D/4-1
    const float* src = c + (size_t)o * D + d4 * 4;
    ct[(size_t)d4 * O + o] = make_float4(src[0], src[1], src[2], src[3]);
}

// Kernel 1: partial sums, symmetric 4x4 register tile.
// Wave covers ALL 256 o (lane + 64g) x 4 b rows; block = 4 waves = 16 b rows.
// Per q-step per thread: 4 coalesced c loads + 4 wave-uniform x loads feed
// 192 VALU ops -> VMEM return traffic 2 MB/CU, under the 10.2 us VALU floor.
// 16 independent accumulator chains provide the ILP.
__global__ __launch_bounds__(256, 4) void dist_part(const float* __restrict__ x,
                                                    const float4* __restrict__ ct,
                                                    float* __restrict__ s1p,
                                                    float* __restrict__ s2p)
{
    const int t  = threadIdx.x;
    const int l  = t & 63;                    // lane: o = l + 64*g
    const int w  = t >> 6;                    // wave 0..3
    const int b0 = blockIdx.x * BB + w * KB;  // first b row of this wave
    const int ds = blockIdx.y;
    const int q0 = ds * NQ;                   // global float4-step base

    const float4* cp = ct + (size_t)q0 * O + l;                 // +64g, step O per q
    const float4* xp = (const float4*)(x + (size_t)b0 * D) + q0; // row stride D/4

    float s1[OT][KB], s2[OT][KB];
    #pragma unroll
    for (int g = 0; g < OT; ++g)
        #pragma unroll
        for (int k = 0; k < KB; ++k) { s1[g][k] = 0.f; s2[g][k] = 0.f; }

    #pragma unroll 4
    for (int q = 0; q < NQ; ++q) {
        float4 cv[OT], xv[KB];
        #pragma unroll
        for (int g = 0; g < OT; ++g) cv[g] = cp[(size_t)q * O + g * 64];
        #pragma unroll
        for (int k = 0; k < KB; ++k) xv[k] = xp[(size_t)k * (D / 4) + q];

        #pragma unroll
        for (int g = 0; g < OT; ++g) {
            #pragma unroll
            for (int k = 0; k < KB; ++k) {
                const float d0 = xv[k].x - cv[g].x, d1 = xv[k].y - cv[g].y,
                            d2 = xv[k].z - cv[g].z, d3 = xv[k].w - cv[g].w;
                s1[g][k] += __builtin_fabsf(d0); s2[g][k] = __builtin_fmaf(d0, d0, s2[g][k]);
                s1[g][k] += __builtin_fabsf(d1); s2[g][k] = __builtin_fmaf(d1, d1, s2[g][k]);
                s1[g][k] += __builtin_fabsf(d2); s2[g][k] = __builtin_fmaf(d2, d2, s2[g][k]);
                s1[g][k] += __builtin_fabsf(d3); s2[g][k] = __builtin_fmaf(d3, d3, s2[g][k]);
            }
        }
    }

    #pragma unroll
    for (int g = 0; g < OT; ++g) {
        #pragma unroll
        for (int k = 0; k < KB; ++k) {
            const size_t idx = ((size_t)ds * B + (b0 + k)) * O + (l + 64 * g);
            s1p[idx] = s1[g][k];
            s2p[idx] = s2[g][k];
        }
    }
}

// Kernel 2: combine D-slices, sqrt + temperature + alpha row-correction.
__global__ __launch_bounds__(256) void combine_kernel(const float* __restrict__ s1p,
                                                      const float* __restrict__ s2p,
                                                      float* __restrict__ out)
{
    const int b = blockIdx.x;
    const int o = threadIdx.x;

    float a1 = 0.f, a2 = 0.f;
    #pragma unroll
    for (int ds = 0; ds < DS; ++ds) {
        const size_t idx = ((size_t)ds * B + b) * O + o;
        a1 += s1p[idx];
        a2 += s2p[idx];
    }
    const float v = a1 + 0.5f * __builtin_sqrtf(a2);

    float t = v;
    #pragma unroll
    for (int off = 32; off >= 1; off >>= 1)
        t += __shfl_down(t, off, 64);

    __shared__ float ws[4];
    if ((o & 63) == 0) ws[o >> 6] = t;
    __syncthreads();
    const float S = ws[0] + ws[1] + ws[2] + ws[3];

    out[(size_t)b * O + o] = ALPHA * S - (1.0f + ALPHA) * v;
}

extern "C" void kernel_launch(void* const* d_in, const int* in_sizes, int n_in,
                              void* d_out, int out_size, void* d_ws, size_t ws_size,
                              hipStream_t stream) {
    const float* x = (const float*)d_in[0];   // [B, D]
    const float* c = (const float*)d_in[1];   // [O, D]
    float* out = (float*)d_out;               // [B, O]

    float*  s1p = (float*)d_ws;                          // [DS, B, O] = 16.8 MB
    float*  s2p = s1p + (size_t)DS * B * O;              // [DS, B, O] = 16.8 MB
    float4* ct  = (float4*)(s2p + (size_t)DS * B * O);   // [D/4, O]   = 1 MB

    transpose_c<<<D / 4, O, 0, stream>>>(c, ct);

    dim3 grid(B / BB, DS);                    // (64, 16) = 1024 blocks
    dist_part<<<grid, 256, 0, stream>>>(x, ct, s1p, s2p);
    combine_kernel<<<B, 256, 0, stream>>>(s1p, s2p, out);
}

// Round 8
// 95.752 us; speedup vs baseline: 1.0468x; 1.0468x over previous
//
#include <hip/hip_runtime.h>
#include <math.h>

#define B 1024
#define O 256
#define D 1024
#define ALPHA 0.005f

#define DS  16           // D splits (blockIdx.y)
#define DCH (D / DS)     // 64 d per block
#define NQ  (DCH / 4)    // 16 float4 steps
#define KB  16           // b rows per block
#define KW  8            // b rows per half-block (wgrp)

// Kernel 0: transpose c[O][D] -> ct[D/4][O] (float4 elements)
__global__ __launch_bounds__(256) void transpose_c(const float* __restrict__ c,
                                                   float4* __restrict__ ct)
{
    const int o  = threadIdx.x;         // 0..255
    const int d4 = blockIdx.x;          // 0..D/4-1
    const float* src = c + (size_t)o * D + d4 * 4;
    ct[(size_t)d4 * O + o] = make_float4(src[0], src[1], src[2], src[3]);
}

// Kernel 1: partial sums. Inner loop runs on LDS + registers only:
//  - x-tile (16 rows x 64 d = 4 KB) staged to LDS once; in-loop x reads are
//    wave-uniform ds_read_b128 -> hardware broadcast, conflict-free (m136),
//    zero VMEM, zero VGPR buffering.
//  - c: 2 per-lane coalesced loads per q-step (o2, o2+128), 2-deep pipelined;
//    4 waves/SIMD x ~400cy compute covers the latency even if serialized.
// Per thread-q: 192 VALU + 8 LDS + 2 VMEM.
__global__ __launch_bounds__(256, 4) void dist_part(const float* __restrict__ x,
                                                    const float4* __restrict__ ct,
                                                    float2* __restrict__ sp)
{
    const int t  = threadIdx.x;
    const int o2 = t & 127;                   // o pair: (o2, o2+128)
    const int wg = t >> 7;                    // half-block: rows wg*8..wg*8+7
    const int b0 = blockIdx.x * KB;
    const int ds = blockIdx.y;
    const int q0 = ds * NQ;

    __shared__ float xs[KB][DCH];             // 4 KB

    // stage x-tile: thread t -> row t>>4, float4 t&15 (coalesced per 16-lane group)
    {
        const int row = t >> 4;
        const int f4  = t & 15;
        const float4 v = *((const float4*)(x + (size_t)(b0 + row) * D + q0 * 4) + f4);
        *((float4*)&xs[row][0] + f4) = v;
    }
    __syncthreads();

    const float4* cp = ct + (size_t)q0 * O + o2;

    float s1[2][KW], s2[2][KW];
    #pragma unroll
    for (int j = 0; j < 2; ++j)
        #pragma unroll
        for (int k = 0; k < KW; ++k) { s1[j][k] = 0.f; s2[j][k] = 0.f; }

    float4 cv0 = cp[0];
    float4 cv1 = cp[128];

    for (int q = 0; q < NQ; ++q) {
        const float4 c0 = cv0;
        const float4 c1 = cv1;
        if (q + 1 < NQ) {                     // prefetch next c pair
            cv0 = cp[(size_t)(q + 1) * O];
            cv1 = cp[(size_t)(q + 1) * O + 128];
        }

        #pragma unroll
        for (int k = 0; k < KW; ++k) {
            const float4 xv = *(const float4*)&xs[wg * KW + k][q * 4];

            float d0 = xv.x - c0.x, d1 = xv.y - c0.y,
                  d2 = xv.z - c0.z, d3 = xv.w - c0.w;
            s1[0][k] += __builtin_fabsf(d0); s2[0][k] = __builtin_fmaf(d0, d0, s2[0][k]);
            s1[0][k] += __builtin_fabsf(d1); s2[0][k] = __builtin_fmaf(d1, d1, s2[0][k]);
            s1[0][k] += __builtin_fabsf(d2); s2[0][k] = __builtin_fmaf(d2, d2, s2[0][k]);
            s1[0][k] += __builtin_fabsf(d3); s2[0][k] = __builtin_fmaf(d3, d3, s2[0][k]);

            d0 = xv.x - c1.x; d1 = xv.y - c1.y;
            d2 = xv.z - c1.z; d3 = xv.w - c1.w;
            s1[1][k] += __builtin_fabsf(d0); s2[1][k] = __builtin_fmaf(d0, d0, s2[1][k]);
            s1[1][k] += __builtin_fabsf(d1); s2[1][k] = __builtin_fmaf(d1, d1, s2[1][k]);
            s1[1][k] += __builtin_fabsf(d2); s2[1][k] = __builtin_fmaf(d2, d2, s2[1][k]);
            s1[1][k] += __builtin_fabsf(d3); s2[1][k] = __builtin_fmaf(d3, d3, s2[1][k]);
        }
    }

    #pragma unroll
    for (int j = 0; j < 2; ++j)
        #pragma unroll
        for (int k = 0; k < KW; ++k) {
            const size_t idx = ((size_t)ds * B + (b0 + wg * KW + k)) * O + o2 + j * 128;
            sp[idx] = make_float2(s1[j][k], s2[j][k]);
        }
}

// Kernel 2: combine D-slices, sqrt + temperature + alpha row-correction.
__global__ __launch_bounds__(256) void combine_kernel(const float2* __restrict__ sp,
                                                      float* __restrict__ out)
{
    const int b = blockIdx.x;
    const int o = threadIdx.x;

    float a1 = 0.f, a2 = 0.f;
    #pragma unroll
    for (int ds = 0; ds < DS; ++ds) {
        const float2 v2 = sp[((size_t)ds * B + b) * O + o];
        a1 += v2.x;
        a2 += v2.y;
    }
    const float v = a1 + 0.5f * __builtin_sqrtf(a2);

    float t = v;
    #pragma unroll
    for (int off = 32; off >= 1; off >>= 1)
        t += __shfl_down(t, off, 64);

    __shared__ float ws[4];
    if ((o & 63) == 0) ws[o >> 6] = t;
    __syncthreads();
    const float S = ws[0] + ws[1] + ws[2] + ws[3];

    out[(size_t)b * O + o] = ALPHA * S - (1.0f + ALPHA) * v;
}

extern "C" void kernel_launch(void* const* d_in, const int* in_sizes, int n_in,
                              void* d_out, int out_size, void* d_ws, size_t ws_size,
                              hipStream_t stream) {
    const float* x = (const float*)d_in[0];   // [B, D]
    const float* c = (const float*)d_in[1];   // [O, D]
    float* out = (float*)d_out;               // [B, O]

    float2* sp = (float2*)d_ws;                          // [DS, B, O] float2 = 33.6 MB
    float4* ct = (float4*)((float*)d_ws + (size_t)2 * DS * B * O); // [D/4, O] = 1 MB

    transpose_c<<<D / 4, O, 0, stream>>>(c, ct);

    dim3 grid(B / KB, DS);                    // (64, 16) = 1024 blocks
    dist_part<<<grid, 256, 0, stream>>>(x, ct, sp);
    combine_kernel<<<B, 256, 0, stream>>>(sp, out);
}